// Round 10
// baseline (331.128 us; speedup 1.0000x reference)
//
#include <hip/hip_runtime.h>
#include <stdint.h>

// positional_spiking_attention — v10: counted-vmcnt pipelined i8 GEMM (T4).
// Spikes {0,1} as u8 (exact). Weights w = s1*a1 + s2*a2 (i8 planes); i32 MFMA
// accumulation exact -> bitwise = v7/v9. Near-threshold columns (|m-0.5|<1e-3)
// compacted + recomputed with bit-exact serial fp32 chain.
// Row layout: r = bi*4 + t; lane's 4 accum regs = T=4 steps of one column.
//
// GEMM: 128x128 tile, BK=64 (8 steps), TWO 24KB LDS buffers (48KB -> 3
// blocks/CU). Per step: vmcnt(6) [counted — next buffer's 6 loads stay in
// flight] -> barrier -> 12 ds_read_b128 + 32 MFMA (setprio) -> barrier ->
// stage step t+2 into the freed buffer. vmcnt hits 0 only at the last step.
//
// Workspace:
//   0    xsb  u8 first-LIF spikes [bi*4+t][512] (8MB)
//   8M   qs / 16M ks / 24M vs / 32M sA  (u8, same layout)
//   40M  Wq   4 mats x 2 planes x 512x512 i8 (2MB, plane-major flat)
//   44M  scl  [mat][2][512] f32 scales
//   48M  list u32 flagged ids (cap 5M) ; 70M cnt

#define T_ 4
#define B_ 4
#define L_ 1024
#define D_ 512
#define BI_ (B_*L_)                 // 4096 (b,l) columns
#define STRIDE4 (B_*L_*D_/4)        // 524288 4-elem groups per t-slice
#define INV_STD 0.9999950000374997f
#define EPS_FLAG 1e-3f
#define LIST_CAP 5000000u

typedef unsigned int   u32;
typedef unsigned char  u8;
typedef int i32x4 __attribute__((ext_vector_type(4)));

static __device__ __forceinline__ float spike_of(float m) {
  return m > 0.5f ? 1.0f : 0.0f;
}

__device__ __forceinline__ void gll16(const void* g, void* l) {
  __builtin_amdgcn_global_load_lds(
      (const __attribute__((address_space(1))) u32*)g,
      (__attribute__((address_space(3))) u32*)l, 16, 0, 0);
}

template <int N>
__device__ __forceinline__ void vwait() {
  asm volatile("s_waitcnt vmcnt(%0)" :: "n"(N) : "memory");
}

// ------ weight quantize: w = s1*a1 + s2*a2, plane-major flat (v7 layout) ----
__global__ __launch_bounds__(256) void k_wsplit(const float* __restrict__ qw,
    const float* __restrict__ kw, const float* __restrict__ vw,
    const float* __restrict__ lw, u8* __restrict__ Wq,
    float* __restrict__ scl, u32* __restrict__ cnt) {
  if (blockIdx.x == 0 && threadIdx.x == 0) *cnt = 0;
  int gid = blockIdx.x * 4 + (threadIdx.x >> 6);   // wave id 0..2047
  int mat = gid >> 9, e = gid & 511;
  int lane = threadIdx.x & 63;
  const float* W = mat == 0 ? qw : mat == 1 ? kw : mat == 2 ? vw : lw;
  const float4* w4 = (const float4*)(W + (size_t)e * 512 + lane * 8);
  float4 wa = w4[0], wb = w4[1];
  float w[8] = {wa.x, wa.y, wa.z, wa.w, wb.x, wb.y, wb.z, wb.w};
  float am = 0.f;
#pragma unroll
  for (int j = 0; j < 8; ++j) am = fmaxf(am, fabsf(w[j]));
#pragma unroll
  for (int off = 1; off < 64; off <<= 1)
    am = fmaxf(am, __shfl_xor(am, off, 64));
  float s1 = am > 0.f ? am * (1.0f / 127.0f) : 1.0f;
  float s2 = s1 * (1.0f / 254.0f);
  float inv1 = 1.0f / s1, inv2 = 1.0f / s2;
  u32 p1lo = 0, p1hi = 0, p2lo = 0, p2hi = 0;
#pragma unroll
  for (int j = 0; j < 8; ++j) {
    float q1 = rintf(w[j] * inv1);
    q1 = fminf(127.f, fmaxf(-127.f, q1));
    float r = w[j] - s1 * q1;
    float q2 = rintf(r * inv2);
    q2 = fminf(127.f, fmaxf(-127.f, q2));
    u32 b1 = (u32)(u8)(signed char)(int)q1;
    u32 b2 = (u32)(u8)(signed char)(int)q2;
    if (j < 4) { p1lo |= b1 << (j * 8); p2lo |= b2 << (j * 8); }
    else       { p1hi |= b1 << ((j - 4) * 8); p2hi |= b2 << ((j - 4) * 8); }
  }
  u8* base = Wq + (size_t)mat * 524288 + (size_t)e * 512 + lane * 8;
  *(uint2*)base            = make_uint2(p1lo, p1hi);   // plane 0
  *(uint2*)(base + 262144) = make_uint2(p2lo, p2hi);   // plane 1
  if (lane == 0) {
    scl[mat * 1024 + e] = s1;
    scl[mat * 1024 + 512 + e] = s2;
  }
}

// ---------------- first LIF: x[t][bi][d] -> xsb[bi*4+t][d] (u8) -------------
__global__ __launch_bounds__(256) void k_lif_first(const float* __restrict__ x,
                                                   u8* __restrict__ xsb) {
  int idx = blockIdx.x * 256 + threadIdx.x;       // bi*128 + d4
  if (idx >= STRIDE4) return;
  const int bi = idx >> 7, d4 = idx & 127;
  const float4* x4 = (const float4*)x;
  uchar4* o4 = (uchar4*)xsb;
  float m[4], s[4];
  float4 v = x4[idx];
  m[0] = v.x; m[1] = v.y; m[2] = v.z; m[3] = v.w;
#pragma unroll
  for (int c = 0; c < 4; ++c) s[c] = spike_of(m[c]);
  o4[(bi * 4 + 0) * 128 + d4] =
      make_uchar4((u8)s[0], (u8)s[1], (u8)s[2], (u8)s[3]);
#pragma unroll
  for (int t = 1; t < T_; ++t) {
    v = x4[idx + t * STRIDE4];
    float xv[4] = {v.x, v.y, v.z, v.w};
#pragma unroll
    for (int c = 0; c < 4; ++c) {
      m[c] = m[c] * 0.25f * (1.0f - s[c]) + xv[c];
      s[c] = spike_of(m[c]);
    }
    o4[(bi * 4 + t) * 128 + d4] =
        make_uchar4((u8)s[0], (u8)s[1], (u8)s[2], (u8)s[3]);
  }
}

// ======= counted-vmcnt pipelined i8 GEMM core ===============================
template <int T, int VM>
__device__ __forceinline__ void k_step(const u8* const (&gsrc)[6],
    const int (&loff)[6], u8* sm, const int (&offA)[4],
    const int (&offB)[2][4], i32x4 (&acc)[4][4][2]) {
  vwait<VM>();                              // counted: buf[T&1]'s loads landed
  __builtin_amdgcn_s_barrier();
  const u8* bb = sm + (T & 1) * 24576;
  uint4 af[4], bf[8];
#pragma unroll
  for (int mi = 0; mi < 4; ++mi) af[mi] = *(const uint4*)(bb + offA[mi]);
#pragma unroll
  for (int pl = 0; pl < 2; ++pl)
#pragma unroll
    for (int ni = 0; ni < 4; ++ni)
      bf[pl * 4 + ni] = *(const uint4*)(bb + offB[pl][ni]);
  __builtin_amdgcn_s_setprio(1);
#pragma unroll
  for (int pl = 0; pl < 2; ++pl)
#pragma unroll
    for (int ni = 0; ni < 4; ++ni)
#pragma unroll
      for (int mi = 0; mi < 4; ++mi)
        acc[mi][ni][pl] = __builtin_amdgcn_mfma_i32_16x16x64_i8(
            __builtin_bit_cast(i32x4, af[mi]),
            __builtin_bit_cast(i32x4, bf[pl * 4 + ni]),
            acc[mi][ni][pl], 0, 0, 0);
  __builtin_amdgcn_s_setprio(0);
  __builtin_amdgcn_s_barrier();             // all waves done reading buf[T&1]
  if constexpr (T + 2 < 8) {                // refill the freed buffer
#pragma unroll
    for (int u = 0; u < 6; ++u)
      gll16(gsrc[u] + ((T + 2) << 6), sm + (T & 1) * 24576 + loff[u]);
  }
}

__device__ __forceinline__ void gemm_pipe(const u8* __restrict__ Ab,
    const u8* __restrict__ Wp, int row0, int col0, int tid,
    u8* sm, i32x4 (&acc)[4][4][2]) {
  const u8* gsrc[6];
  int loff[6];
#pragma unroll
  for (int u = 0; u < 6; ++u) {
    int lin = u * 4096 + tid * 16;
    if (u < 2) {                            // A: 8KB, rows of 64B (4x16B)
      int r = lin >> 6, sl = (lin >> 4) & 3;
      gsrc[u] = Ab + (size_t)(row0 + r) * 512 + sl * 16;
    } else {                                // B: 2 planes x 8KB
      int b = lin - 8192;
      int pl = b >> 13, l3 = b & 8191;
      int r = l3 >> 6, sl = (l3 >> 4) & 3;
      gsrc[u] = Wp + (size_t)pl * 262144 + (size_t)(col0 + r) * 512 + sl * 16;
    }
    loff[u] = lin;
  }
  const int lane = tid & 63;
  const int wr = (tid >> 6) >> 1, wc = (tid >> 6) & 1;
  const int la = lane & 15, lg = lane >> 4;
  int offA[4], offB[2][4];
#pragma unroll
  for (int mi = 0; mi < 4; ++mi)
    offA[mi] = (wr * 64 + mi * 16 + la) * 64 + lg * 16;
#pragma unroll
  for (int pl = 0; pl < 2; ++pl)
#pragma unroll
    for (int ni = 0; ni < 4; ++ni)
      offB[pl][ni] = 8192 + pl * 8192 + (wc * 64 + ni * 16 + la) * 64 + lg * 16;

#pragma unroll
  for (int a = 0; a < 4; ++a)
#pragma unroll
    for (int b = 0; b < 4; ++b)
#pragma unroll
      for (int pl = 0; pl < 2; ++pl) acc[a][b][pl] = (i32x4){0, 0, 0, 0};

  // prologue: stage k-steps 0 and 1 (12 loads in flight)
#pragma unroll
  for (int u = 0; u < 6; ++u) gll16(gsrc[u], sm + loff[u]);
#pragma unroll
  for (int u = 0; u < 6; ++u) gll16(gsrc[u] + 64, sm + 24576 + loff[u]);

  k_step<0, 6>(gsrc, loff, sm, offA, offB, acc);
  k_step<1, 6>(gsrc, loff, sm, offA, offB, acc);
  k_step<2, 6>(gsrc, loff, sm, offA, offB, acc);
  k_step<3, 6>(gsrc, loff, sm, offA, offB, acc);
  k_step<4, 6>(gsrc, loff, sm, offA, offB, acc);
  k_step<5, 6>(gsrc, loff, sm, offA, offB, acc);
  k_step<6, 6>(gsrc, loff, sm, offA, offB, acc);
  k_step<7, 0>(gsrc, loff, sm, offA, offB, acc);
}

// ------ fused QKV: GEMM + BN + LIF epilogue, LDS-staged coalesced stores ----
__global__ __launch_bounds__(256) void k_gemm_qkv(const u8* __restrict__ Ab,
    const u8* __restrict__ Wq, const float* __restrict__ scl,
    const float* __restrict__ qb2, const float* __restrict__ qg,
    const float* __restrict__ qbe,
    const float* __restrict__ kb2, const float* __restrict__ kg,
    const float* __restrict__ kbe,
    const float* __restrict__ vb2, const float* __restrict__ vg,
    const float* __restrict__ vbe,
    u8* __restrict__ qs, u8* __restrict__ ks_, u8* __restrict__ vs,
    u32* __restrict__ list, u32* __restrict__ cnt) {
  __shared__ __align__(16) u8 sm[49152];
  const int tid = threadIdx.x;
  const int tz = blockIdx.z;
  const u8* Wp = Wq + (size_t)tz * 524288;
  const float* Bb = tz == 0 ? qb2 : tz == 1 ? kb2 : vb2;
  const float* Gg = tz == 0 ? qg  : tz == 1 ? kg  : vg;
  const float* Be = tz == 0 ? qbe : tz == 1 ? kbe : vbe;
  u8* S           = tz == 0 ? qs  : tz == 1 ? ks_ : vs;

  int f = blockIdx.y * 4 + blockIdx.x;
  int tI = (f & 7) * 64 + (f >> 3);              // XCD-chunked tile swizzle
  const int row0 = (tI >> 2) * 128;
  const int col0 = (tI & 3) * 128;

  i32x4 acc[4][4][2];
  gemm_pipe(Ab, Wp, row0, col0, tid, sm, acc);

  const int lane = tid & 63;
  const int wr = (tid >> 6) >> 1, wc = (tid >> 6) & 1;
  const int la = lane & 15, lg = lane >> 4;

  u8* sm8 = sm;                         // 128x128 u8 spike tile (16KB, buf0)
#pragma unroll
  for (int ni = 0; ni < 4; ++ni) {
    int cl = wc * 64 + ni * 16 + la;    // local col
    int e = col0 + cl;
    float s1 = scl[tz * 1024 + e];
    float s2 = scl[tz * 1024 + 512 + e];
    float cs = INV_STD * Gg[e];
    float cb = Bb[e], ct = Be[e];
#pragma unroll
    for (int mi = 0; mi < 4; ++mi) {
      int rl = wr * 64 + mi * 16 + lg * 4;   // local row base (bi*4 aligned)
      int bi = (row0 + rl) >> 2;
      float m = 0.f, sp = 0.f;
      int fl = 0;
#pragma unroll
      for (int p = 0; p < 4; ++p) {          // p == t
        float raw = s1 * (float)acc[mi][ni][0][p] +
                    s2 * (float)acc[mi][ni][1][p];
        float pre = (raw + cb) * cs + ct;
        if (p == 0) m = pre;
        else m = m * 0.25f * (1.0f - sp) + pre;
        sp = spike_of(m);
        if (fabsf(m - 0.5f) < EPS_FLAG) fl = 1;
        sm8[(rl + p) * 128 + cl] = (u8)sp;
      }
      if (fl) {
        u32 pos = atomicAdd(cnt, 1u);
        if (pos < LIST_CAP)
          list[pos] = ((u32)tz << 21) | (u32)(bi * 512 + e);
      }
    }
  }
  __syncthreads();
  // coalesced write-out: 4 passes x 32 rows, 16B per lane (128B/row segments)
#pragma unroll
  for (int ps = 0; ps < 4; ++ps) {
    int rr = ps * 32 + (tid >> 3);
    int c16 = (tid & 7) * 16;
    uint4 vv = *(const uint4*)(sm8 + rr * 128 + c16);
    *(uint4*)(S + (size_t)(row0 + rr) * 512 + col0 + c16) = vv;
  }
}

// -------- last GEMM + BN -> fp32 out [t][bi][d], LDS-staged stores ----------
__global__ __launch_bounds__(256) void k_gemm_out(const u8* __restrict__ Ab,
    const u8* __restrict__ Wq, const float* __restrict__ scl,
    const float* __restrict__ bias, const float* __restrict__ gamma,
    const float* __restrict__ beta, float* __restrict__ Y) {
  __shared__ __align__(16) u8 sm[49152];
  const int tid = threadIdx.x;
  int f = blockIdx.y * 4 + blockIdx.x;
  int tI = (f & 7) * 64 + (f >> 3);
  const int row0 = (tI >> 2) * 128;
  const int col0 = (tI & 3) * 128;

  i32x4 acc[4][4][2];
  gemm_pipe(Ab, Wq + 3u * 524288, row0, col0, tid, sm, acc);

  const int lane = tid & 63;
  const int wr = (tid >> 6) >> 1, wc = (tid >> 6) & 1;
  const int la = lane & 15, lg = lane >> 4;

  float* sm32 = (float*)sm;             // 64x128 f32 tile per pass (32KB)
#pragma unroll
  for (int h = 0; h < 2; ++h) {
    if (wr == h) {
#pragma unroll
      for (int ni = 0; ni < 4; ++ni) {
        int cl = wc * 64 + ni * 16 + la;
        int e = col0 + cl;
        float s1 = scl[3 * 1024 + e];
        float s2 = scl[3 * 1024 + 512 + e];
        float cs = INV_STD * gamma[e];
        float cb = bias[e], ct = beta[e];
#pragma unroll
        for (int mi = 0; mi < 4; ++mi) {
          int rb = mi * 16 + lg * 4;         // local row within pass
#pragma unroll
          for (int p = 0; p < 4; ++p) {
            float raw = s1 * (float)acc[mi][ni][0][p] +
                        s2 * (float)acc[mi][ni][1][p];
            sm32[(rb + p) * 128 + cl] = (raw + cb) * cs + ct;
          }
        }
      }
    }
    __syncthreads();
    int rl = tid >> 2;                   // 0..63
    int q0 = (tid & 3) * 32;             // float offset
    int gr = row0 + h * 64 + rl;         // global spike-row = bi*4+p
    int bi = gr >> 2, p = gr & 3;
    float* dst = Y + ((size_t)p * BI_ + bi) * 512 + col0 + q0;
    const float* srcl = sm32 + rl * 128 + q0;
#pragma unroll
    for (int u = 0; u < 8; ++u)
      ((uint4*)dst)[u] = ((const uint4*)srcl)[u];
    __syncthreads();
  }
}

// ------- fixup: quad-per-item, exact serial fp32 chain, shfl-combine --------
__device__ __forceinline__ void consume32_u8(const float4 (&wb)[8],
                                             const uint4 (&ab)[2], float& c) {
#pragma unroll
  for (int u = 0; u < 8; ++u) {           // u = group of 4 consecutive j
    float4 w = wb[u];
    uint4 t = ab[u >> 2];
    u32 word = (u & 3) == 0 ? t.x : (u & 3) == 1 ? t.y
             : (u & 3) == 2 ? t.z : t.w;
    c += (word & 0xFFu)       ? w.x : 0.0f;   // strict ascending-j order
    c += (word & 0xFF00u)     ? w.y : 0.0f;
    c += (word & 0xFF0000u)   ? w.z : 0.0f;
    c += (word >> 24)         ? w.w : 0.0f;
  }
}

__global__ __launch_bounds__(128) void k_fixup_c(const u8* __restrict__ xsb,
    u8* __restrict__ qs, u8* __restrict__ ks, u8* __restrict__ vs,
    const float* __restrict__ qw, const float* __restrict__ qb2,
    const float* __restrict__ qg, const float* __restrict__ qbe,
    const float* __restrict__ kw, const float* __restrict__ kb2,
    const float* __restrict__ kg, const float* __restrict__ kbe,
    const float* __restrict__ vw, const float* __restrict__ vb2,
    const float* __restrict__ vg, const float* __restrict__ vbe,
    const u32* __restrict__ list, const u32* __restrict__ cnt) {
  u32 n = *cnt;
  if (n > LIST_CAP) n = LIST_CAP;
  u32 tot = n * 4;
  for (u32 ii = blockIdx.x * 128 + threadIdx.x; ii < tot;
       ii += gridDim.x * 128) {
    u32 i = ii >> 2;
    int t = (int)(ii & 3);
    u32 e = list[i];
    int tz = (int)(e >> 21);
    int col = (int)(e & 0x1FFFFFu);
    int bi = col >> 9, d = col & 511;
    const float* W  = tz == 0 ? qw  : tz == 1 ? kw  : vw;
    const float* Bb = tz == 0 ? qb2 : tz == 1 ? kb2 : vb2;
    const float* Gg = tz == 0 ? qg  : tz == 1 ? kg  : vg;
    const float* Be = tz == 0 ? qbe : tz == 1 ? kbe : vbe;
    u8* S           = tz == 0 ? qs  : tz == 1 ? ks  : vs;
    const float4* w4 = (const float4*)(W + (size_t)d * 512);            // 128
    const uint4*  R  = (const uint4*)(xsb + ((size_t)bi * 4 + t) * 512); // 32

    float4 wA[8], wB[8];
    uint4 aA[2], aB[2];
#pragma unroll
    for (int u = 0; u < 8; ++u) wA[u] = w4[u];
#pragma unroll
    for (int u = 0; u < 2; ++u) aA[u] = R[u];
    float c = 0.f;
#pragma unroll
    for (int ch = 0; ch < 16; ++ch) {     // 16 chunks x 32 j
      if ((ch & 1) == 0) {
        if (ch + 1 < 16) {
          int wb0 = (ch + 1) * 8, ab0 = (ch + 1) * 2;
#pragma unroll
          for (int u = 0; u < 8; ++u) wB[u] = w4[wb0 + u];
#pragma unroll
          for (int u = 0; u < 2; ++u) aB[u] = R[ab0 + u];
        }
        consume32_u8(wA, aA, c);
      } else {
        if (ch + 1 < 16) {
          int wb0 = (ch + 1) * 8, ab0 = (ch + 1) * 2;
#pragma unroll
          for (int u = 0; u < 8; ++u) wA[u] = w4[wb0 + u];
#pragma unroll
          for (int u = 0; u < 2; ++u) aA[u] = R[ab0 + u];
        }
        consume32_u8(wB, aB, c);
      }
    }
    int lane = threadIdx.x & 63;
    int qb = lane & ~3;
    float cq[4];
    cq[0] = __shfl(c, qb + 0, 64);
    cq[1] = __shfl(c, qb + 1, 64);
    cq[2] = __shfl(c, qb + 2, 64);
    cq[3] = __shfl(c, qb + 3, 64);
    float cs = INV_STD * Gg[d];
    float cb = Bb[d], ct = Be[d];
    float m = 0.f, s = 0.f;
    u8 myb = 0;
#pragma unroll
    for (int t2 = 0; t2 < 4; ++t2) {
      float pre = (cq[t2] + cb) * cs + ct;   // identical to GEMM epilogue form
      if (t2 == 0) m = pre;
      else m = m * 0.25f * (1.0f - s) + pre;
      s = spike_of(m);
      if (t2 == t) myb = (u8)s;
    }
    S[((size_t)bi * 4 + t) * 512 + d] = myb;
  }
}

// ---------------- banded positional mixing + attn_lif (u8) ------------------
__global__ __launch_bounds__(256) void k_attn(const u8* __restrict__ qs,
    const u8* __restrict__ ks, const u8* __restrict__ vs,
    const float* __restrict__ pos_bias, u8* __restrict__ sout) {
  int idx = blockIdx.x * 256 + threadIdx.x;     // bi*128 + d4
  if (idx >= STRIDE4) return;
  const int d4 = idx & 127;
  const int bi = idx >> 7;
  const int i = bi & (L_ - 1);
  const int wmax = i < 7 ? i : 7;

  float pbv[8];
  const float* pbrow = pos_bias + (size_t)i * L_ + i;
  for (int w = 0; w <= wmax; ++w) pbv[w] = pbrow[-w];

  const uchar4* k4 = (const uchar4*)ks;
  const uchar4* v4 = (const uchar4*)vs;
  const uchar4* q4 = (const uchar4*)qs;
  float pre[T_][4];

#pragma unroll
  for (int t = 0; t < T_; ++t) {
    float sum[4] = {0.f, 0.f, 0.f, 0.f};
    for (int w = wmax; w >= 0; --w) {   // ascending j = i-w
      int rj = ((bi - w) * 4 + t) * 128 + d4;
      uchar4 ku = k4[rj];
      uchar4 vu = v4[rj];
      sum[0] += (ku.x && vu.x) ? pbv[w] : 0.0f;
      sum[1] += (ku.y && vu.y) ? pbv[w] : 0.0f;
      sum[2] += (ku.z && vu.z) ? pbv[w] : 0.0f;
      sum[3] += (ku.w && vu.w) ? pbv[w] : 0.0f;
    }
    uchar4 qu = q4[(bi * 4 + t) * 128 + d4];
    pre[t][0] = qu.x ? sum[0] : 0.0f;
    pre[t][1] = qu.y ? sum[1] : 0.0f;
    pre[t][2] = qu.z ? sum[2] : 0.0f;
    pre[t][3] = qu.w ? sum[3] : 0.0f;
  }

  uchar4* s4 = (uchar4*)sout;
  float m[4], s[4];
#pragma unroll
  for (int c = 0; c < 4; ++c) { m[c] = pre[0][c]; s[c] = spike_of(m[c]); }
  s4[(bi * 4 + 0) * 128 + d4] =
      make_uchar4((u8)s[0], (u8)s[1], (u8)s[2], (u8)s[3]);
#pragma unroll
  for (int t = 1; t < T_; ++t) {
#pragma unroll
    for (int c = 0; c < 4; ++c) {
      m[c] = m[c] * 0.25f * (1.0f - s[c]) + pre[t][c];
      s[c] = spike_of(m[c]);
    }
    s4[(bi * 4 + t) * 128 + d4] =
        make_uchar4((u8)s[0], (u8)s[1], (u8)s[2], (u8)s[3]);
  }
}

extern "C" void kernel_launch(void* const* d_in, const int* in_sizes, int n_in,
                              void* d_out, int out_size, void* d_ws, size_t ws_size,
                              hipStream_t stream) {
  (void)in_sizes; (void)n_in; (void)out_size; (void)ws_size;
  const float* x        = (const float*)d_in[0];
  const float* pos_bias = (const float*)d_in[1];
  const float* q_w    = (const float*)d_in[2];
  const float* q_b    = (const float*)d_in[3];
  const float* q_g    = (const float*)d_in[4];
  const float* q_beta = (const float*)d_in[5];
  const float* k_w    = (const float*)d_in[6];
  const float* k_b    = (const float*)d_in[7];
  const float* k_g    = (const float*)d_in[8];
  const float* k_beta = (const float*)d_in[9];
  const float* v_w    = (const float*)d_in[10];
  const float* v_b    = (const float*)d_in[11];
  const float* v_g    = (const float*)d_in[12];
  const float* v_beta = (const float*)d_in[13];
  const float* last_w    = (const float*)d_in[14];
  const float* last_b    = (const float*)d_in[15];
  const float* last_g    = (const float*)d_in[16];
  const float* last_beta = (const float*)d_in[17];
  float* out = (float*)d_out;

  char* ws = (char*)d_ws;
  u8*    xsb  = (u8*)(ws + 0);
  u8*    qs   = (u8*)(ws + 8388608);
  u8*    ks   = (u8*)(ws + 16777216);
  u8*    vs   = (u8*)(ws + 25165824);
  u8*    sA   = (u8*)(ws + 33554432);
  u8*    Wq   = (u8*)(ws + 41943040);      // 4 x 524288
  float* scl  = (float*)(ws + 46137344);   // 4 x 1024 f32
  u32*   list = (u32*)(ws + 50331648);     // 20 MB cap
  u32*   cnt  = (u32*)(ws + 73400320);

  k_wsplit<<<512, 256, 0, stream>>>(q_w, k_w, v_w, last_w, Wq, scl, cnt);
  k_lif_first<<<2048, 256, 0, stream>>>(x, xsb);

  dim3 gq(4, 128, 3);
  k_gemm_qkv<<<gq, 256, 0, stream>>>(xsb, Wq, scl,
      q_b, q_g, q_beta, k_b, k_g, k_beta, v_b, v_g, v_beta,
      qs, ks, vs, list, cnt);

  k_fixup_c<<<2048, 128, 0, stream>>>(xsb, qs, ks, vs,
      q_w, q_b, q_g, q_beta, k_w, k_b, k_g, k_beta, v_w, v_b, v_g, v_beta,
      list, cnt);

  k_attn<<<2048, 256, 0, stream>>>(qs, ks, vs, pos_bias, sA);

  dim3 gg(4, 128);
  k_gemm_out<<<gg, 256, 0, stream>>>(sA, Wq, scl,
                                     last_b, last_g, last_beta, out);
}